// Round 11
// baseline (19.010 us; speedup 1.0000x reference)
//
#include <hip/hip_runtime.h>
#include <hip/hip_bf16.h>

#define NQ 6
#define DIM 64
#define NL 6

typedef _Float16 half8 __attribute__((ext_vector_type(8)));
typedef float f32x16 __attribute__((ext_vector_type(16)));

// ---------------------------------------------------------------------------
// Kernel 1 (v5): one WAVE per column of C (lane k holds amplitude k); gate
// chain verified (rounds 5-10). Output scattered in 32x32x16-MFMA frag order:
//   A-frag (ttile T, kstep S): lane l holds rows m=l&31 of k_out tile T,
//   k_in slots = S*16 + (l>>5)*8 + e, e=0..7 (one dwordx4 per lane).
//   halfword idx = ri*4096 + ((T*4+S)*64 + lane')*8 + e.
// This wave computes column kin=col: S=col>>4, h'=(col>>3)&1, e=col&7;
// lane `row` scatters to T=row>>5, lane' = h'*32 + (row&31).
// ---------------------------------------------------------------------------
__global__ __launch_bounds__(256) void build_C_kernel(const float* __restrict__ w,
                                                      unsigned short* __restrict__ Cu) {
    __shared__ __align__(16) float Uc[NL * NQ][8];
    const int tid  = threadIdx.x;
    const int lane = tid & 63;
    const int wave = tid >> 6;
    const int col  = blockIdx.x * 4 + wave;

    if (tid < NL * NQ) {
        float phi = w[3 * tid], th = w[3 * tid + 1], om = w[3 * tid + 2];
        float ch = cosf(0.5f * th), sh = sinf(0.5f * th);
        float ap = -0.5f * (phi + om), am = -0.5f * (phi - om);
        float epr = cosf(ap), epi = sinf(ap);
        float emr = cosf(am), emi = sinf(am);
        Uc[tid][0] =  epr * ch;  // u00r
        Uc[tid][1] =  epi * ch;  // u00i
        Uc[tid][2] = -emr * sh;  // u01r
        Uc[tid][3] =  emi * sh;  // u01i
        Uc[tid][4] =  emr * sh;  // u10r
        Uc[tid][5] =  emi * sh;  // u10i
        Uc[tid][6] =  epr * ch;  // u11r
        Uc[tid][7] = -epi * ch;  // u11i
    }
    __syncthreads();

    float re = (lane == col) ? 1.f : 0.f;
    float im = 0.f;

    #pragma unroll
    for (int l = 0; l < NL; ++l) {
        #pragma unroll
        for (int j = 0; j < NQ; ++j) {
            const int g = l * NQ + j;
            const int m = 1 << (5 - j);
            float4 uA = *(const float4*)&Uc[g][0];  // u00r u00i u01r u01i
            float4 uB = *(const float4*)&Uc[g][4];  // u10r u10i u11r u11i
            float pr = __shfl_xor(re, m);
            float pi = __shfl_xor(im, m);
            const bool hi = (lane & m) != 0;
            float Ar = hi ? uB.z : uA.x;
            float Ai = hi ? uB.w : uA.y;
            float Br = hi ? uB.x : uA.z;
            float Bi = hi ? uB.y : uA.w;
            float nr = Ar * re - Ai * im + Br * pr - Bi * pi;
            float ni = Ar * im + Ai * re + Br * pi + Bi * pr;
            re = nr; im = ni;
        }
        // fused CNOT-ring permutation: new[k] = old[src(k)]
        const int r = l % (NQ - 1) + 1;
        int src = lane;
        #pragma unroll
        for (int jj = NQ - 1; jj >= 0; --jj) {
            int cm = 1 << (5 - jj);
            int tm = 1 << (5 - ((jj + r) % NQ));
            src = (src & cm) ? (src ^ tm) : src;
        }
        re = __shfl(re, src);
        im = __shfl(im, src);
    }

    // scatter into 32x32-frag order (one-time 16 KB)
    _Float16 hr = (_Float16)re, hi16 = (_Float16)im;
    const int S  = col >> 4;
    const int hp = (col >> 3) & 1;
    const int e  = col & 7;
    const int T  = lane >> 5;
    const int m  = lane & 31;
    const int lp = hp * 32 + m;
    const int base = ((T * 4 + S) * 64 + lp) * 8 + e;
    Cu[base]        = __builtin_bit_cast(unsigned short, hr);
    Cu[4096 + base] = __builtin_bit_cast(unsigned short, hi16);
}

// ---------------------------------------------------------------------------
// Kernel 2 (v5): 32x32x16 MFMA, zero LDS, zero barriers.
// Wave = 32 samples. Lane (h=lane>>5, n=lane&31) serves sample n: builds its
// B-frags in registers: B[S][e] = psi[k=S*16+h*8+e] = F(S,h)*G(e) with
// F = (S&2?sn0:cs0)(S&1?sn1:cs1)(h?sn2:cs2), G(e) = prod of qubits 3,4,5.
// Y = C*Psi via 2 ttiles x 4 ksteps x {Re,Im} = 16 MFMA / 32 samples.
// D layout (HW-verified m74/m101): col=lane&31, row=(reg&3)+8*(reg>>2)+4*h;
// k_out = T*32+row -> sign bits: j0<-T, j1<-reg&8, j2<-reg&4, j3<-h,
// j4<-reg&2, j5<-reg&1. Walsh-tree epilogue; single h-fold (6 shfl).
// ---------------------------------------------------------------------------
__global__ __launch_bounds__(256, 4) void qexp_mfma(const float* __restrict__ x,
                                                    const unsigned* __restrict__ C,
                                                    float* __restrict__ out,
                                                    int batch) {
    const int tid  = threadIdx.x;
    const int lane = tid & 63;
    const int wave = tid >> 6;
    const int n    = lane & 31;
    const int h    = lane >> 5;
    const int sample = blockIdx.x * 128 + wave * 32 + n;
    if (sample >= batch) return;

    // ---- per-lane trig for its sample
    const float2* xp = (const float2*)(x + (size_t)sample * NQ);
    float2 x01 = xp[0], x23 = xp[1], x45 = xp[2];
    float xa[6] = {x01.x, x01.y, x23.x, x23.y, x45.x, x45.y};
    float cs[6], sn[6];
    #pragma unroll
    for (int j = 0; j < 6; ++j) {
        float a = 1.57079632679489662f * xa[j];
        __sincosf(a, &sn[j], &cs[j]);
    }

    // ---- G(e): qubits 3,4,5 by e bits (b2=q3, b1=q4, b0=q5)
    float b00 = cs[3] * cs[4], b01 = cs[3] * sn[4];
    float b10 = sn[3] * cs[4], b11 = sn[3] * sn[4];
    float lo[8] = {b00 * cs[5], b00 * sn[5], b01 * cs[5], b01 * sn[5],
                   b10 * cs[5], b10 * sn[5], b11 * cs[5], b11 * sn[5]};
    float fh = h ? sn[2] : cs[2];

    // ---- B-frags: 4 ksteps, packed with the same (h,e)->k map as A
    half8 B[4];
    #pragma unroll
    for (int S = 0; S < 4; ++S) {
        float F = ((S & 2) ? sn[0] : cs[0]) * ((S & 1) ? sn[1] : cs[1]) * fh;
        int4 d;
        d.x = __builtin_bit_cast(int, __builtin_amdgcn_cvt_pkrtz(F * lo[0], F * lo[1]));
        d.y = __builtin_bit_cast(int, __builtin_amdgcn_cvt_pkrtz(F * lo[2], F * lo[3]));
        d.z = __builtin_bit_cast(int, __builtin_amdgcn_cvt_pkrtz(F * lo[4], F * lo[5]));
        d.w = __builtin_bit_cast(int, __builtin_amdgcn_cvt_pkrtz(F * lo[6], F * lo[7]));
        B[S] = __builtin_bit_cast(half8, d);
    }

    // ---- 2 ttiles sequentially (caps live acc at 32 VGPR)
    float Pt[2], o1t[2], o2t[2], o4t[2], o5t[2];
    #pragma unroll
    for (int T = 0; T < 2; ++T) {
        f32x16 cr = (f32x16)0.f, ci = (f32x16)0.f;
        #pragma unroll
        for (int S = 0; S < 4; ++S) {
            int dw = ((T * 4 + S) * 64 + lane) * 4;
            half8 Afr = __builtin_bit_cast(half8, *(const int4*)(C + dw));
            half8 Afi = __builtin_bit_cast(half8, *(const int4*)(C + 2048 + dw));
            cr = __builtin_amdgcn_mfma_f32_32x32x16_f16(Afr, B[S], cr, 0, 0, 0);
            ci = __builtin_amdgcn_mfma_f32_32x32x16_f16(Afi, B[S], ci, 0, 0, 0);
        }
        // Walsh-tree partial sums over reg bits
        float p[16];
        #pragma unroll
        for (int r2 = 0; r2 < 16; ++r2)
            p[r2] = fmaf(cr[r2], cr[r2], ci[r2] * ci[r2]);
        float e0[8], t5 = 0.f;
        #pragma unroll
        for (int i2 = 0; i2 < 8; ++i2) {
            e0[i2] = p[2 * i2] + p[2 * i2 + 1];
            t5 += p[2 * i2] - p[2 * i2 + 1];
        }
        float e1[4], t4 = 0.f;
        #pragma unroll
        for (int i2 = 0; i2 < 4; ++i2) {
            e1[i2] = e0[2 * i2] + e0[2 * i2 + 1];
            t4 += e0[2 * i2] - e0[2 * i2 + 1];
        }
        float f0 = e1[0] + e1[1], f1 = e1[2] + e1[3];
        o2t[T] = (e1[0] - e1[1]) + (e1[2] - e1[3]);
        Pt[T]  = f0 + f1;
        o1t[T] = f0 - f1;
        o4t[T] = t4;
        o5t[T] = t5;
    }

    float P  = Pt[0] + Pt[1];
    float o0 = Pt[0] - Pt[1];                 // j=0: sign = bit5 = T
    float o1 = o1t[0] + o1t[1];               // j=1: reg&8
    float o2 = o2t[0] + o2t[1];               // j=2: reg&4
    float o4 = o4t[0] + o4t[1];               // j=4: reg&2
    float o5 = o5t[0] + o5t[1];               // j=5: reg&1
    float o3 = __builtin_bit_cast(float, __builtin_bit_cast(unsigned, P) ^ ((unsigned)h << 31));

    // h-fold (lanes n and n+32)
    o0 += __shfl_xor(o0, 32);
    o1 += __shfl_xor(o1, 32);
    o2 += __shfl_xor(o2, 32);
    o3 += __shfl_xor(o3, 32);
    o4 += __shfl_xor(o4, 32);
    o5 += __shfl_xor(o5, 32);

    float2* op = (float2*)(out + (size_t)sample * 6);
    if (h == 0) { op[0] = make_float2(o0, o1); op[1] = make_float2(o2, o3); }
    else        { op[2] = make_float2(o4, o5); }
}

extern "C" void kernel_launch(void* const* d_in, const int* in_sizes, int n_in,
                              void* d_out, int out_size, void* d_ws, size_t ws_size,
                              hipStream_t stream) {
    const float* x = (const float*)d_in[0];
    const float* w = (const float*)d_in[1];
    unsigned* C = (unsigned*)d_ws;   // 4096 dwords = 16 KB (frag-ordered Re|Im)
    float* out = (float*)d_out;
    const int batch = in_sizes[0] / NQ;

    build_C_kernel<<<16, 256, 0, stream>>>(w, (unsigned short*)C);
    const int blocks = (batch + 127) / 128;   // 2048 blocks x 256 threads
    qexp_mfma<<<blocks, 256, 0, stream>>>(x, C, out, batch);
}